// Round 3
// baseline (212.368 us; speedup 1.0000x reference)
//
#include <hip/hip_runtime.h>
#include <hip/hip_cooperative_groups.h>

namespace cg = cooperative_groups;

#define CCH 256
#define HH  256
#define WW  256
#define HWSZ (HH * WW)
#define NROI 512
#define RBIN 7
#define NBIN (RBIN * RBIN)                    // 49
#define NTASK (2 * NBIN)                      // 98 (bin, point-pair) tasks
#define TFEAT_BYTES ((size_t)HWSZ * CCH * 2)  // 32 MiB bf16 HWC

typedef float vfloat4 __attribute__((ext_vector_type(4)));

__device__ __forceinline__ unsigned short f2bf_rne(float f) {
    unsigned u = __float_as_uint(f);
    u = (u + 0x7fffu + ((u >> 16) & 1u)) >> 16;
    return (unsigned short)u;
}

// ================= R14: single cooperative kernel ==========================
// Phase 1: transpose (C,H,W) fp32 -> (H,W,C) bf16, 8 tiles/block.
//   1024-thread tile mapping, same XOR swizzle as the proven 2-kernel
//   version. Per-wave conflict check:
//     write: cl = t>>4 in {4w..4w+3} -> (cl>>2)&7 == w&7 const per wave;
//       p = 4*(fc ^ (w&7)) is a 16-slot permutation per row -> free.
//     read: bank = r + 4*((w ^ (fc4&7))&7), r in 0..3 -> 32 banks x 2 lanes.
// grid.sync() (device-scope fence: cross-XCD tfeat visibility).
// Phase 2: R13 fused sample+pool+broadcast, n = blockIdx.x (512 rois).
// Co-residency: 512 blocks x 1024 thr = 2 blocks/CU exactly;
//   __launch_bounds__(1024,8) caps VGPR at 64; LDS 25.3 KB/block.
__global__ __launch_bounds__(1024, 8)
void roialign_onekernel(const float* __restrict__ feat,
                        const float* __restrict__ rois,
                        float* __restrict__ out,
                        unsigned short* __restrict__ tfeat)
{
    cg::grid_group grid = cg::this_grid();

    // union'd LDS: phase1 tile = 64*64 floats (16384 B);
    //              phase2 tmax = 98*64 floats (25088 B)
    __shared__ __align__(16) float smem[NTASK * 64];
    __shared__ float pooled[NBIN];

    const int t   = threadIdx.x;              // 0..1023
    const int bid = blockIdx.x;               // 0..511

    // ---- roi params preloaded before the transpose (hides the tiny load) --
    const int n = bid;
    const float y0 = rois[n * 4 + 0];
    const float x0 = rois[n * 4 + 1];
    const float sh = (rois[n * 4 + 2] - y0) * (1.0f / (float)RBIN);
    const float sw = (rois[n * 4 + 3] - x0) * (1.0f / (float)RBIN);

    // ---- Phase 1: transpose 8 tiles -------------------------------------
    {
        const int cl  = t >> 4;               // 0..63 (write pass row)
        const int fc  = t & 15;               // float4 col
        const int p   = (4 * fc) ^ (4 * ((cl >> 2) & 7));
        const int hl  = t >> 4;               // 0..63 (read pass row)
        const int fc4 = t & 15;
        const int cl_w = fc4 * 4;
        const int pc   = hl ^ (4 * (fc4 & 7));

        #pragma unroll 1
        for (int it = 0; it < 8; ++it) {
            const int tile = bid + it * NROI; // 0..4095
            const int hw0  = (tile & 1023) * 64;
            const int c0   = (tile >> 10) * 64;

            const vfloat4 v = __builtin_nontemporal_load(
                (const vfloat4*)(feat + (size_t)(c0 + cl) * HWSZ + hw0 + 4 * fc));
            if (it) __syncthreads();          // previous read pass done
            *(vfloat4*)&smem[cl * 64 + p] = v;            // ds_write_b128
            __syncthreads();

            ushort4 w;
            w.x = f2bf_rne(smem[(cl_w + 0) * 64 + pc]);
            w.y = f2bf_rne(smem[(cl_w + 1) * 64 + pc]);
            w.z = f2bf_rne(smem[(cl_w + 2) * 64 + pc]);
            w.w = f2bf_rne(smem[(cl_w + 3) * 64 + pc]);
            // 16 lanes (same hl) cover 64 consecutive channels -> 128 B seg
            *(ushort4*)(tfeat + (size_t)(hw0 + hl) * CCH + c0 + cl_w) = w;
        }
    }

    grid.sync();                              // tfeat visible device-wide

    // ---- Phase 2: fused sample + pool + broadcast (R13 body) -------------
    {
        const int wave = t >> 6;              // 0..15
        const int lane = t & 63;
        const int half = lane >> 5;           // point selector within pair
        const int cOff = (lane & 31) * 8;     // 8 channels per lane

        #pragma unroll 2
        for (int task = wave; task < NTASK; task += 16) {
            const int bin = task >> 1;
            const int i   = task & 1;         // which point-pair (sy row)
            const int by  = bin / RBIN;
            const int bx  = bin - by * RBIN;

            const int point = i * 2 + half;   // 0..3
            const int sy = point >> 1;
            const int sx = point & 1;

            const float y = y0 + sh * (float)by +
                            ((sy == 0) ? (sh * (1.0f / 3.0f)) : (sh * (2.0f / 3.0f)));
            const float x = x0 + sw * (float)bx +
                            ((sx == 0) ? (sw * (1.0f / 3.0f)) : (sw * (2.0f / 3.0f)));

            int iy1 = (int)floorf(y);
            int iy2 = iy1 + 1;
            int ix1 = (int)floorf(x);
            int ix2 = ix1 + 1;
            iy1 = min(max(iy1, 0), HH - 1);
            iy2 = min(max(iy2, 0), HH - 1);
            ix1 = min(max(ix1, 0), WW - 1);
            ix2 = min(max(ix2, 0), WW - 1);

            // weights from clipped indices (matches reference)
            const float wy1 = y - (float)iy1;
            const float wy2 = (float)iy2 - y;
            const float wx1 = x - (float)ix1;
            const float wx2 = (float)ix2 - x;

            const uint4 A = *(const uint4*)(tfeat + (size_t)(iy1 * WW + ix1) * CCH + cOff);
            const uint4 B = *(const uint4*)(tfeat + (size_t)(iy1 * WW + ix2) * CCH + cOff);
            const uint4 C = *(const uint4*)(tfeat + (size_t)(iy2 * WW + ix1) * CCH + cOff);
            const uint4 D = *(const uint4*)(tfeat + (size_t)(iy2 * WW + ix2) * CCH + cOff);
            const unsigned* ap = (const unsigned*)&A;
            const unsigned* bp = (const unsigned*)&B;
            const unsigned* cp = (const unsigned*)&C;
            const unsigned* dp = (const unsigned*)&D;

            float m = -INFINITY;
            #pragma unroll
            for (int k = 0; k < 4; ++k) {
                const unsigned ua = ap[k], ub = bp[k], uc = cp[k], ud = dp[k];
                {
                    const float f11 = __uint_as_float(ua << 16);
                    const float f12 = __uint_as_float(ub << 16);
                    const float f21 = __uint_as_float(uc << 16);
                    const float f22 = __uint_as_float(ud << 16);
                    const float p2 = f11 * wx2 + f12 * wx1;
                    const float q2 = f21 * wx2 + f22 * wx1;
                    m = fmaxf(m, p2 * wy2 + q2 * wy1);
                }
                {
                    const float f11 = __uint_as_float(ua & 0xffff0000u);
                    const float f12 = __uint_as_float(ub & 0xffff0000u);
                    const float f21 = __uint_as_float(uc & 0xffff0000u);
                    const float f22 = __uint_as_float(ud & 0xffff0000u);
                    const float p2 = f11 * wx2 + f12 * wx1;
                    const float q2 = f21 * wx2 + f22 * wx1;
                    m = fmaxf(m, p2 * wy2 + q2 * wy1);
                }
            }

            smem[task * 64 + lane] = m;       // one ds_write, no conflicts
        }
        __syncthreads();

        // 16 threads per bin reduce 128 partials (2 tasks x 64 lanes)
        if (t < NBIN * 16) {
            const int b = t >> 4;
            const int j = t & 15;
            const float* src = &smem[b * 128 + j * 8];
            const vfloat4 a = *(const vfloat4*)(src);
            const vfloat4 c = *(const vfloat4*)(src + 4);
            float m = fmaxf(fmaxf(fmaxf(a.x, a.y), fmaxf(a.z, a.w)),
                            fmaxf(fmaxf(c.x, c.y), fmaxf(c.z, c.w)));
            #pragma unroll
            for (int off = 8; off > 0; off >>= 1)
                m = fmaxf(m, __shfl_xor(m, off, 16));
            if (j == 0) pooled[b] = m;
        }
        __syncthreads();

        // broadcast (C x 49) as dwordx4: 3136 float4 per roi, 16B aligned
        float* o = out + (size_t)n * (CCH * NBIN);
        #pragma unroll
        for (int k = 0; k < 4; ++k) {
            const int idx4 = t + k * 1024;
            if (idx4 < (CCH * NBIN) / 4) {
                int r = (idx4 * 4) % NBIN;
                vfloat4 v;
                v.x = pooled[r]; r = (r == NBIN - 1) ? 0 : r + 1;
                v.y = pooled[r]; r = (r == NBIN - 1) ? 0 : r + 1;
                v.z = pooled[r]; r = (r == NBIN - 1) ? 0 : r + 1;
                v.w = pooled[r];
                __builtin_nontemporal_store(v, (vfloat4*)o + idx4);
            }
        }
    }
}

// ================= Fallback path (proven 2-kernel R13) =====================
__global__ __launch_bounds__(256)
void transpose_chw_to_hwc_bf16(const float* __restrict__ feat,
                               unsigned short* __restrict__ tfeat)
{
    __shared__ __align__(16) float tile[64 * 64];
    const int t   = threadIdx.x;
    const int hw0 = blockIdx.x * 64;
    const int c0  = blockIdx.y * 64;

    const int cl_r = t >> 4;
    const int fc   = t & 15;

    vfloat4 v[4];
    #pragma unroll
    for (int j = 0; j < 4; ++j) {
        v[j] = __builtin_nontemporal_load(
            (const vfloat4*)(feat + (size_t)(c0 + cl_r + j * 16) * HWSZ + hw0 + 4 * fc));
    }
    #pragma unroll
    for (int j = 0; j < 4; ++j) {
        const int cl = cl_r + j * 16;
        const int p  = (4 * fc) ^ (4 * ((cl >> 2) & 7));
        *(vfloat4*)&tile[cl * 64 + p] = v[j];
    }
    __syncthreads();

    const int cl_w = (t & 15) * 4;
    const int swz  = 4 * ((t & 15) & 7);
    #pragma unroll
    for (int j = 0; j < 4; ++j) {
        const int hl = (t >> 4) + j * 16;
        const int pc = hl ^ swz;
        ushort4 w;
        w.x = f2bf_rne(tile[(cl_w + 0) * 64 + pc]);
        w.y = f2bf_rne(tile[(cl_w + 1) * 64 + pc]);
        w.z = f2bf_rne(tile[(cl_w + 2) * 64 + pc]);
        w.w = f2bf_rne(tile[(cl_w + 3) * 64 + pc]);
        *(ushort4*)(tfeat + (size_t)(hw0 + hl) * CCH + c0 + cl_w) = w;
    }
}

__global__ __launch_bounds__(1024, 8)
void roialign_fused(const unsigned short* __restrict__ tfeat,
                    const float* __restrict__ rois,
                    float* __restrict__ out)
{
    const int n    = blockIdx.x;
    const int t    = threadIdx.x;
    const int wave = t >> 6;
    const int lane = t & 63;
    const int half = lane >> 5;
    const int cOff = (lane & 31) * 8;

    __shared__ __align__(16) float tmax[NTASK * 64];
    __shared__ float pooled[NBIN];

    const float y0 = rois[n * 4 + 0];
    const float x0 = rois[n * 4 + 1];
    const float sh = (rois[n * 4 + 2] - y0) * (1.0f / (float)RBIN);
    const float sw = (rois[n * 4 + 3] - x0) * (1.0f / (float)RBIN);

    #pragma unroll 2
    for (int task = wave; task < NTASK; task += 16) {
        const int bin = task >> 1;
        const int i   = task & 1;
        const int by  = bin / RBIN;
        const int bx  = bin - by * RBIN;

        const int point = i * 2 + half;
        const int sy = point >> 1;
        const int sx = point & 1;

        const float y = y0 + sh * (float)by +
                        ((sy == 0) ? (sh * (1.0f / 3.0f)) : (sh * (2.0f / 3.0f)));
        const float x = x0 + sw * (float)bx +
                        ((sx == 0) ? (sw * (1.0f / 3.0f)) : (sw * (2.0f / 3.0f)));

        int iy1 = (int)floorf(y);
        int iy2 = iy1 + 1;
        int ix1 = (int)floorf(x);
        int ix2 = ix1 + 1;
        iy1 = min(max(iy1, 0), HH - 1);
        iy2 = min(max(iy2, 0), HH - 1);
        ix1 = min(max(ix1, 0), WW - 1);
        ix2 = min(max(ix2, 0), WW - 1);

        const float wy1 = y - (float)iy1;
        const float wy2 = (float)iy2 - y;
        const float wx1 = x - (float)ix1;
        const float wx2 = (float)ix2 - x;

        const uint4 A = *(const uint4*)(tfeat + (size_t)(iy1 * WW + ix1) * CCH + cOff);
        const uint4 B = *(const uint4*)(tfeat + (size_t)(iy1 * WW + ix2) * CCH + cOff);
        const uint4 C = *(const uint4*)(tfeat + (size_t)(iy2 * WW + ix1) * CCH + cOff);
        const uint4 D = *(const uint4*)(tfeat + (size_t)(iy2 * WW + ix2) * CCH + cOff);
        const unsigned* ap = (const unsigned*)&A;
        const unsigned* bp = (const unsigned*)&B;
        const unsigned* cp = (const unsigned*)&C;
        const unsigned* dp = (const unsigned*)&D;

        float m = -INFINITY;
        #pragma unroll
        for (int k = 0; k < 4; ++k) {
            const unsigned ua = ap[k], ub = bp[k], uc = cp[k], ud = dp[k];
            {
                const float f11 = __uint_as_float(ua << 16);
                const float f12 = __uint_as_float(ub << 16);
                const float f21 = __uint_as_float(uc << 16);
                const float f22 = __uint_as_float(ud << 16);
                const float p = f11 * wx2 + f12 * wx1;
                const float q = f21 * wx2 + f22 * wx1;
                m = fmaxf(m, p * wy2 + q * wy1);
            }
            {
                const float f11 = __uint_as_float(ua & 0xffff0000u);
                const float f12 = __uint_as_float(ub & 0xffff0000u);
                const float f21 = __uint_as_float(uc & 0xffff0000u);
                const float f22 = __uint_as_float(ud & 0xffff0000u);
                const float p = f11 * wx2 + f12 * wx1;
                const float q = f21 * wx2 + f22 * wx1;
                m = fmaxf(m, p * wy2 + q * wy1);
            }
        }

        tmax[task * 64 + lane] = m;
    }
    __syncthreads();

    if (t < NBIN * 16) {
        const int b = t >> 4;
        const int j = t & 15;
        const float* src = &tmax[b * 128 + j * 8];
        const vfloat4 a = *(const vfloat4*)(src);
        const vfloat4 c = *(const vfloat4*)(src + 4);
        float m = fmaxf(fmaxf(fmaxf(a.x, a.y), fmaxf(a.z, a.w)),
                        fmaxf(fmaxf(c.x, c.y), fmaxf(c.z, c.w)));
        #pragma unroll
        for (int off = 8; off > 0; off >>= 1)
            m = fmaxf(m, __shfl_xor(m, off, 16));
        if (j == 0) pooled[b] = m;
    }
    __syncthreads();

    float* o = out + (size_t)n * (CCH * NBIN);
    #pragma unroll
    for (int k = 0; k < 4; ++k) {
        const int idx4 = t + k * 1024;
        if (idx4 < (CCH * NBIN) / 4) {
            int r = (idx4 * 4) % NBIN;
            vfloat4 v;
            v.x = pooled[r]; r = (r == NBIN - 1) ? 0 : r + 1;
            v.y = pooled[r]; r = (r == NBIN - 1) ? 0 : r + 1;
            v.z = pooled[r]; r = (r == NBIN - 1) ? 0 : r + 1;
            v.w = pooled[r];
            __builtin_nontemporal_store(v, (vfloat4*)o + idx4);
        }
    }
}

__global__ __launch_bounds__(256)
void roialign_direct_kernel(const float* __restrict__ feat,
                            const float* __restrict__ rois,
                            float* __restrict__ out)
{
    const int n = blockIdx.x;
    const int t = threadIdx.x;
    __shared__ float ptmax[196];
    __shared__ float pooled[NBIN];

    const float y0  = rois[n * 4 + 0];
    const float x0  = rois[n * 4 + 1];
    const float sh  = (rois[n * 4 + 2] - y0) / (float)RBIN;
    const float sw  = (rois[n * 4 + 3] - x0) / (float)RBIN;

    const bool active = (t < 196);
    int off11 = 0, off12 = 0, off21 = 0, off22 = 0;
    float wx1 = 0.f, wx2 = 0.f, wy1 = 0.f, wy2 = 0.f;
    if (active) {
        const int py = t / 14, px = t % 14;
        const int by = py >> 1, sy = py & 1;
        const int bx = px >> 1, sx = px & 1;
        const float y = y0 + sh * (float)by + ((sy == 0) ? (sh / 3.0f) : (2.0f * sh / 3.0f));
        const float x = x0 + sw * (float)bx + ((sx == 0) ? (sw / 3.0f) : (2.0f * sw / 3.0f));
        int iy1 = (int)floorf(y), iy2 = iy1 + 1;
        int ix1 = (int)floorf(x), ix2 = ix1 + 1;
        iy1 = min(max(iy1, 0), HH - 1); iy2 = min(max(iy2, 0), HH - 1);
        ix1 = min(max(ix1, 0), WW - 1); ix2 = min(max(ix2, 0), WW - 1);
        wy1 = y - (float)iy1; wy2 = (float)iy2 - y;
        wx1 = x - (float)ix1; wx2 = (float)ix2 - x;
        off11 = iy1 * WW + ix1; off12 = iy1 * WW + ix2;
        off21 = iy2 * WW + ix1; off22 = iy2 * WW + ix2;
    }
    if (active) {
        float m = -INFINITY;
        const float* f = feat;
        #pragma unroll 4
        for (int c = 0; c < CCH; ++c) {
            const float p = f[off11] * wx2 + f[off12] * wx1;
            const float q = f[off21] * wx2 + f[off22] * wx1;
            m = fmaxf(m, p * wy2 + q * wy1);
            f += HWSZ;
        }
        ptmax[t] = m;
    }
    __syncthreads();
    if (t < NBIN) {
        const int by = t / RBIN, bx = t % RBIN;
        const int p00 = (2 * by) * 14 + 2 * bx;
        pooled[t] = fmaxf(fmaxf(ptmax[p00], ptmax[p00 + 1]),
                          fmaxf(ptmax[p00 + 14], ptmax[p00 + 15]));
    }
    __syncthreads();
    float* o = out + (size_t)n * (CCH * NBIN);
    for (int idx = t; idx < CCH * NBIN; idx += 256)
        o[idx] = pooled[idx % NBIN];
}

extern "C" void kernel_launch(void* const* d_in, const int* in_sizes, int n_in,
                              void* d_out, int out_size, void* d_ws, size_t ws_size,
                              hipStream_t stream)
{
    const float* feat = (const float*)d_in[0];   // (256,256,256) fp32
    const float* rois = (const float*)d_in[1];   // (512,4) fp32
    float* out = (float*)d_out;                  // (512,256,7,7) fp32

    if (ws_size < TFEAT_BYTES) {
        roialign_direct_kernel<<<NROI, 256, 0, stream>>>(feat, rois, out);
        return;
    }

    unsigned short* tfeat = (unsigned short*)d_ws;

    // --- preferred: single cooperative kernel (kills one dispatch gap) ----
    void* args[] = { (void*)&feat, (void*)&rois, (void*)&out, (void*)&tfeat };
    hipError_t e = hipLaunchCooperativeKernel((void*)roialign_onekernel,
                                              dim3(NROI), dim3(1024),
                                              args, 0, stream);
    if (e == hipSuccess) return;
    (void)hipGetLastError();                     // clear sticky error

    // --- fallback: proven 2-kernel path -----------------------------------
    dim3 tgrid(HWSZ / 64, CCH / 64);
    transpose_chw_to_hwc_bf16<<<tgrid, 256, 0, stream>>>(feat, tfeat);
    roialign_fused<<<NROI, 1024, 0, stream>>>(tfeat, rois, out);
}

// Round 4
// 131.710 us; speedup vs baseline: 1.6124x; 1.6124x over previous
//
#include <hip/hip_runtime.h>

#define CCH 256
#define HH  256
#define WW  256
#define HWSZ (HH * WW)
#define NROI 512
#define RBIN 7
#define NBIN (RBIN * RBIN)                    // 49
#define NTASK (2 * NBIN)                      // 98 (bin, point-pair) tasks
#define TFEAT_BYTES ((size_t)HWSZ * CCH * 2)  // 32 MiB bf16 HWC

typedef float vfloat4 __attribute__((ext_vector_type(4)));

__device__ __forceinline__ unsigned short f2bf_rne(float f) {
    unsigned u = __float_as_uint(f);
    u = (u + 0x7fffu + ((u >> 16) & 1u)) >> 16;
    return (unsigned short)u;
}

// ---------------- Kernel 1: (C,H,W) fp32 -> (H,W,C) bf16 transpose ----------
// XOR-swizzled LDS, conflict-free in BOTH passes. 4096 independent blocks
// give the cross-block latency hiding the R14 coop merge destroyed
// (R14 post-mortem: 512 blocks x 8 barrier-separated iters = latency-bound,
// 18% HBM, 108 us vs ~27 us for this pair). ~96 MB traffic ~= 15 us floor.
__global__ __launch_bounds__(256)
void transpose_chw_to_hwc_bf16(const float* __restrict__ feat,
                               unsigned short* __restrict__ tfeat)
{
    __shared__ __align__(16) float tile[64 * 64];  // 16 KB, swizzled
    const int t   = threadIdx.x;              // 0..255
    const int hw0 = blockIdx.x * 64;
    const int c0  = blockIdx.y * 64;

    const int cl_r = t >> 4;                  // 0..15 (+j*16)
    const int fc   = t & 15;                  // float4 column 0..15

    vfloat4 v[4];
    #pragma unroll
    for (int j = 0; j < 4; ++j) {
        v[j] = __builtin_nontemporal_load(
            (const vfloat4*)(feat + (size_t)(c0 + cl_r + j * 16) * HWSZ + hw0 + 4 * fc));
    }
    #pragma unroll
    for (int j = 0; j < 4; ++j) {
        const int cl = cl_r + j * 16;
        const int p  = (4 * fc) ^ (4 * ((cl >> 2) & 7));
        *(vfloat4*)&tile[cl * 64 + p] = v[j];          // ds_write_b128
    }
    __syncthreads();

    const int cl_w = (t & 15) * 4;            // 0,4,..,60
    const int swz  = 4 * ((t & 15) & 7);      // == 4*(((cl_w+i)>>2)&7) for i<4
    #pragma unroll
    for (int j = 0; j < 4; ++j) {
        const int hl = (t >> 4) + j * 16;     // 0..63 over passes
        const int pc = hl ^ swz;
        ushort4 w;
        w.x = f2bf_rne(tile[(cl_w + 0) * 64 + pc]);
        w.y = f2bf_rne(tile[(cl_w + 1) * 64 + pc]);
        w.z = f2bf_rne(tile[(cl_w + 2) * 64 + pc]);
        w.w = f2bf_rne(tile[(cl_w + 3) * 64 + pc]);
        // 16 lanes (same hl) cover 64 consecutive channels -> 128 B segment
        *(ushort4*)(tfeat + (size_t)(hw0 + hl) * CCH + c0 + cl_w) = w;
    }
}

// ---------------- Kernel 2: fused sample + pool + broadcast (R13) ----------
// Task = (bin, point-pair); per-lane partial max straight to LDS (no in-loop
// cross-lane reduction); parallel 98x64 -> 49 epilogue; dwordx4 broadcast.
// ~58 MB effective traffic ~= 10 us floor; measured pair total ~27 us.
__global__ __launch_bounds__(1024, 8)
void roialign_fused(const unsigned short* __restrict__ tfeat,
                    const float* __restrict__ rois,
                    float* __restrict__ out)
{
    const int n    = blockIdx.x;
    const int t    = threadIdx.x;
    const int wave = t >> 6;                  // 0..15
    const int lane = t & 63;
    const int half = lane >> 5;               // point selector within pair
    const int cOff = (lane & 31) * 8;         // 8 channels per lane

    __shared__ __align__(16) float tmax[NTASK * 64];  // 25088 B per-lane partials
    __shared__ float pooled[NBIN];

    const float y0 = rois[n * 4 + 0];
    const float x0 = rois[n * 4 + 1];
    const float sh = (rois[n * 4 + 2] - y0) * (1.0f / (float)RBIN);
    const float sw = (rois[n * 4 + 3] - x0) * (1.0f / (float)RBIN);

    #pragma unroll 2
    for (int task = wave; task < NTASK; task += 16) {
        const int bin = task >> 1;
        const int i   = task & 1;             // which point-pair (sy row)
        const int by  = bin / RBIN;
        const int bx  = bin - by * RBIN;

        const int point = i * 2 + half;       // 0..3
        const int sy = point >> 1;
        const int sx = point & 1;

        const float y = y0 + sh * (float)by +
                        ((sy == 0) ? (sh * (1.0f / 3.0f)) : (sh * (2.0f / 3.0f)));
        const float x = x0 + sw * (float)bx +
                        ((sx == 0) ? (sw * (1.0f / 3.0f)) : (sw * (2.0f / 3.0f)));

        int iy1 = (int)floorf(y);
        int iy2 = iy1 + 1;
        int ix1 = (int)floorf(x);
        int ix2 = ix1 + 1;
        iy1 = min(max(iy1, 0), HH - 1);
        iy2 = min(max(iy2, 0), HH - 1);
        ix1 = min(max(ix1, 0), WW - 1);
        ix2 = min(max(ix2, 0), WW - 1);

        // weights from clipped indices (matches reference, incl. edge strip)
        const float wy1 = y - (float)iy1;
        const float wy2 = (float)iy2 - y;
        const float wx1 = x - (float)ix1;
        const float wx2 = (float)ix2 - x;

        const uint4 A = *(const uint4*)(tfeat + (size_t)(iy1 * WW + ix1) * CCH + cOff);
        const uint4 B = *(const uint4*)(tfeat + (size_t)(iy1 * WW + ix2) * CCH + cOff);
        const uint4 C = *(const uint4*)(tfeat + (size_t)(iy2 * WW + ix1) * CCH + cOff);
        const uint4 D = *(const uint4*)(tfeat + (size_t)(iy2 * WW + ix2) * CCH + cOff);
        const unsigned* ap = (const unsigned*)&A;
        const unsigned* bp = (const unsigned*)&B;
        const unsigned* cp = (const unsigned*)&C;
        const unsigned* dp = (const unsigned*)&D;

        float m = -INFINITY;
        #pragma unroll
        for (int k = 0; k < 4; ++k) {
            const unsigned ua = ap[k], ub = bp[k], uc = cp[k], ud = dp[k];
            {
                const float f11 = __uint_as_float(ua << 16);
                const float f12 = __uint_as_float(ub << 16);
                const float f21 = __uint_as_float(uc << 16);
                const float f22 = __uint_as_float(ud << 16);
                const float p = f11 * wx2 + f12 * wx1;
                const float q = f21 * wx2 + f22 * wx1;
                m = fmaxf(m, p * wy2 + q * wy1);
            }
            {
                const float f11 = __uint_as_float(ua & 0xffff0000u);
                const float f12 = __uint_as_float(ub & 0xffff0000u);
                const float f21 = __uint_as_float(uc & 0xffff0000u);
                const float f22 = __uint_as_float(ud & 0xffff0000u);
                const float p = f11 * wx2 + f12 * wx1;
                const float q = f21 * wx2 + f22 * wx1;
                m = fmaxf(m, p * wy2 + q * wy1);
            }
        }

        tmax[task * 64 + lane] = m;           // one ds_write, no conflicts
    }
    __syncthreads();

    // Phase 2: 16 threads per bin reduce 128 partials (2 tasks x 64 lanes).
    if (t < NBIN * 16) {
        const int b = t >> 4;                 // bin
        const int j = t & 15;
        const float* src = &tmax[b * 128 + j * 8];
        const vfloat4 a = *(const vfloat4*)(src);
        const vfloat4 c = *(const vfloat4*)(src + 4);
        float m = fmaxf(fmaxf(fmaxf(a.x, a.y), fmaxf(a.z, a.w)),
                        fmaxf(fmaxf(c.x, c.y), fmaxf(c.z, c.w)));
        #pragma unroll
        for (int off = 8; off > 0; off >>= 1)
            m = fmaxf(m, __shfl_xor(m, off, 16));
        if (j == 0) pooled[b] = m;
    }
    __syncthreads();

    // broadcast (C x 49) as dwordx4: 3136 float4 per roi, 16B aligned
    float* o = out + (size_t)n * (CCH * NBIN);
    #pragma unroll
    for (int k = 0; k < 4; ++k) {
        const int idx4 = t + k * 1024;
        if (idx4 < (CCH * NBIN) / 4) {
            int r = (idx4 * 4) % NBIN;
            vfloat4 v;
            v.x = pooled[r]; r = (r == NBIN - 1) ? 0 : r + 1;
            v.y = pooled[r]; r = (r == NBIN - 1) ? 0 : r + 1;
            v.z = pooled[r]; r = (r == NBIN - 1) ? 0 : r + 1;
            v.w = pooled[r];
            __builtin_nontemporal_store(v, (vfloat4*)o + idx4);
        }
    }
}

// ---------------- Fallback (direct kernel, used if ws too small) -----------
__global__ __launch_bounds__(256)
void roialign_direct_kernel(const float* __restrict__ feat,
                            const float* __restrict__ rois,
                            float* __restrict__ out)
{
    const int n = blockIdx.x;
    const int t = threadIdx.x;
    __shared__ float ptmax[196];
    __shared__ float pooled[NBIN];

    const float y0  = rois[n * 4 + 0];
    const float x0  = rois[n * 4 + 1];
    const float sh  = (rois[n * 4 + 2] - y0) / (float)RBIN;
    const float sw  = (rois[n * 4 + 3] - x0) / (float)RBIN;

    const bool active = (t < 196);
    int off11 = 0, off12 = 0, off21 = 0, off22 = 0;
    float wx1 = 0.f, wx2 = 0.f, wy1 = 0.f, wy2 = 0.f;
    if (active) {
        const int py = t / 14, px = t % 14;
        const int by = py >> 1, sy = py & 1;
        const int bx = px >> 1, sx = px & 1;
        const float y = y0 + sh * (float)by + ((sy == 0) ? (sh / 3.0f) : (2.0f * sh / 3.0f));
        const float x = x0 + sw * (float)bx + ((sx == 0) ? (sw / 3.0f) : (2.0f * sw / 3.0f));
        int iy1 = (int)floorf(y), iy2 = iy1 + 1;
        int ix1 = (int)floorf(x), ix2 = ix1 + 1;
        iy1 = min(max(iy1, 0), HH - 1); iy2 = min(max(iy2, 0), HH - 1);
        ix1 = min(max(ix1, 0), WW - 1); ix2 = min(max(ix2, 0), WW - 1);
        wy1 = y - (float)iy1; wy2 = (float)iy2 - y;
        wx1 = x - (float)ix1; wx2 = (float)ix2 - x;
        off11 = iy1 * WW + ix1; off12 = iy1 * WW + ix2;
        off21 = iy2 * WW + ix1; off22 = iy2 * WW + ix2;
    }
    if (active) {
        float m = -INFINITY;
        const float* f = feat;
        #pragma unroll 4
        for (int c = 0; c < CCH; ++c) {
            const float p = f[off11] * wx2 + f[off12] * wx1;
            const float q = f[off21] * wx2 + f[off22] * wx1;
            m = fmaxf(m, p * wy2 + q * wy1);
            f += HWSZ;
        }
        ptmax[t] = m;
    }
    __syncthreads();
    if (t < NBIN) {
        const int by = t / RBIN, bx = t % RBIN;
        const int p00 = (2 * by) * 14 + 2 * bx;
        pooled[t] = fmaxf(fmaxf(ptmax[p00], ptmax[p00 + 1]),
                          fmaxf(ptmax[p00 + 14], ptmax[p00 + 15]));
    }
    __syncthreads();
    float* o = out + (size_t)n * (CCH * NBIN);
    for (int idx = t; idx < CCH * NBIN; idx += 256)
        o[idx] = pooled[idx % NBIN];
}

extern "C" void kernel_launch(void* const* d_in, const int* in_sizes, int n_in,
                              void* d_out, int out_size, void* d_ws, size_t ws_size,
                              hipStream_t stream)
{
    const float* feat = (const float*)d_in[0];   // (256,256,256) fp32
    const float* rois = (const float*)d_in[1];   // (512,4) fp32
    float* out = (float*)d_out;                  // (512,256,7,7) fp32

    if (ws_size < TFEAT_BYTES) {
        roialign_direct_kernel<<<NROI, 256, 0, stream>>>(feat, rois, out);
        return;
    }

    unsigned short* tfeat = (unsigned short*)d_ws;

    dim3 tgrid(HWSZ / 64, CCH / 64);
    transpose_chw_to_hwc_bf16<<<tgrid, 256, 0, stream>>>(feat, tfeat);

    roialign_fused<<<NROI, 1024, 0, stream>>>(tfeat, rois, out);
}